// Round 1
// baseline (858.924 us; speedup 1.0000x reference)
//
#include <hip/hip_runtime.h>

// 3x3 sliding-window MIN, stride 1, pad 1 (zero pad PARTICIPATES in the min).
// Input/output: fp32 (8, 64, 512, 512). Purely memory-bound: 1 GiB ideal
// traffic -> ~170 us floor at 6.3 TB/s.
//
// R1 change vs previous best (861.3 us): eliminate the two lane-strided
// scalar side-loads (r[-1], r[4]) per row. Each had a 4B/lane payload but a
// 16B lane stride -> same ~16-cache-line wave footprint as the full dwordx4
// load, i.e. 2x the TA/L1 work for 1.25x the data. Neighbor elements come
// from adjacent lanes via __shfl_up/__shfl_down (DS pipe, no vmcnt); only
// lanes 0/63 fall back to a 2-active-lane scalar load at wave boundaries.
// Unroll 4 -> 8 for more loads in flight per wave.

#define H  512
#define W  512
#define CH 64            // rows per thread chunk; read overhead (CH+2)/CH = 1.03x
#define W4 (W / 4)       // 128 column groups of 4
#define CHN (H / CH)     // 8 row chunks
#define NIMG (8 * 64)    // 512 (n,c) images

__device__ __forceinline__ float4 row_hmin(const float* __restrict__ base,
                                           int y, int x0, int lane) {
    // Horizontal 3-min of row y at columns x0..x0+3, zero padding at x=-1,W.
    // Padded rows (y<0 or y>=H) are all zeros -> hmin = 0. The y-range check
    // is wave-uniform (y depends only on the chunk), so the shuffles below
    // always execute convergently.
    if (y < 0 || y >= H) return make_float4(0.f, 0.f, 0.f, 0.f);
    const float* r = base + (size_t)y * W + x0;
    float4 v = *(const float4*)r;                      // aligned 16B load

    // Neighbor elements live in adjacent lanes' registers (lanes hold
    // consecutive column groups): left = lane-1's v.w, right = lane+1's v.x.
    float left  = __shfl_up(v.w, 1, 64);
    float right = __shfl_down(v.x, 1, 64);
    // Wave-boundary lanes: fetch from memory (or zero-pad at image edge).
    // Divergent but only 2 active lanes -> ~2 cache lines of TA work.
    if (lane == 0)  left  = (x0 == 0)     ? 0.0f : r[-1];
    if (lane == 63) right = (x0 == W - 4) ? 0.0f : r[4];

    float4 h;
    h.x = fminf(fminf(left, v.x), v.y);
    h.y = fminf(fminf(v.x,  v.y), v.z);
    h.z = fminf(fminf(v.y,  v.z), v.w);
    h.w = fminf(fminf(v.z,  v.w), right);
    return h;
}

__global__ __launch_bounds__(256) void minpool3x3_kernel(
        const float* __restrict__ in, float* __restrict__ out) {
    int tid   = blockIdx.x * 256 + threadIdx.x;
    int lane  = threadIdx.x & 63;
    int cg    = tid & (W4 - 1);          // column group (consecutive -> coalesced)
    int rest  = tid >> 7;
    int chunk = rest & (CHN - 1);        // wave-uniform
    int img   = rest >> 3;               // wave-uniform

    const float* base  = in  + (size_t)img * H * W;
    float*       obase = out + (size_t)img * H * W;
    int x0 = cg * 4;
    int y0 = chunk * CH;

    // Rolling 3-row buffer of horizontal mins.
    float4 a = row_hmin(base, y0 - 1, x0, lane);
    float4 b = row_hmin(base, y0,     x0, lane);

    #pragma unroll 8
    for (int y = y0; y < y0 + CH; ++y) {
        float4 c = row_hmin(base, y + 1, x0, lane);
        float4 o;
        o.x = fminf(fminf(a.x, b.x), c.x);
        o.y = fminf(fminf(a.y, b.y), c.y);
        o.z = fminf(fminf(a.z, b.z), c.z);
        o.w = fminf(fminf(a.w, b.w), c.w);
        *(float4*)(obase + (size_t)y * W + x0) = o;
        a = b;
        b = c;
    }
}

extern "C" void kernel_launch(void* const* d_in, const int* in_sizes, int n_in,
                              void* d_out, int out_size, void* d_ws, size_t ws_size,
                              hipStream_t stream) {
    const float* x = (const float*)d_in[0];
    float* out = (float*)d_out;
    const int total_threads = NIMG * CHN * W4;   // 524288
    dim3 grid(total_threads / 256), block(256);
    minpool3x3_kernel<<<grid, block, 0, stream>>>(x, out);
}